// Round 1
// baseline (3142.022 us; speedup 1.0000x reference)
//
#include <hip/hip_runtime.h>
#include <hip/hip_bf16.h>
#include <math.h>

// ---------------- types ----------------
typedef __bf16 bf16x8 __attribute__((ext_vector_type(8)));
typedef float f32x4 __attribute__((ext_vector_type(4)));

// ---------------- conversion kernels ----------------
__global__ void cvt_f32_bf16(const float* __restrict__ in, __bf16* __restrict__ out, long n) {
    long i = ((long)blockIdx.x * 256 + threadIdx.x) * 4;
    long stride = (long)gridDim.x * 1024;
    for (; i < n; i += stride) {
        float4 v = *(const float4*)(in + i);
        out[i + 0] = (__bf16)v.x;
        out[i + 1] = (__bf16)v.y;
        out[i + 2] = (__bf16)v.z;
        out[i + 3] = (__bf16)v.w;
    }
}

// transpose + convert: in f32 [M][N] (ldin) -> out bf16 [N][M] (ldout), batched over z
__global__ void transpose_cvt(const float* __restrict__ in, __bf16* __restrict__ out,
                              int ldin, int ldout, long inBS, long outBS) {
    __shared__ __bf16 tile[32][33];
    in  += (long)blockIdx.z * inBS;
    out += (long)blockIdx.z * outBS;
    int n0 = blockIdx.x * 32, m0 = blockIdx.y * 32;
    for (int i = threadIdx.y; i < 32; i += 8)
        tile[i][threadIdx.x] = (__bf16)in[(long)(m0 + i) * ldin + n0 + threadIdx.x];
    __syncthreads();
    for (int i = threadIdx.y; i < 32; i += 8)
        out[(long)(n0 + i) * ldout + m0 + threadIdx.x] = tile[threadIdx.x][i];
}

// ---------------- GEMM: C[M,N] = A[M,K] @ Bt[N,K]^T (+epilogue) ----------------
// OUT: 0 = f32 normal, 1 = bf16 normal, 2 = bf16 transposed (out[n*ldc + m])
template<bool ROWB, bool COLB, bool GELUF, bool RES, int OUT>
__global__ __launch_bounds__(256, 2) void gemm_bf16(
    const __bf16* __restrict__ A, int lda, long aBS,
    const __bf16* __restrict__ Bt, int ldb, long bBS,
    void* __restrict__ outp, int ldc, long cBS,
    const float* __restrict__ rowBias,
    const float* __restrict__ colBias,
    const float* __restrict__ res, int ldres,
    int K)
{
    __shared__ __bf16 Asm[128 * 64];
    __shared__ __bf16 Bsm[128 * 64];
    const int tid = threadIdx.x;
    const int lane = tid & 63, wave = tid >> 6;
    const int wm = wave >> 1, wn = wave & 1;
    const int l15 = lane & 15, l4 = lane >> 4;
    const long m0 = (long)blockIdx.x * 128, n0 = (long)blockIdx.y * 128;
    A  += (long)blockIdx.z * aBS;
    Bt += (long)blockIdx.z * bBS;
    const int srow = tid >> 3;          // 0..31
    const int scol = (tid & 7) * 8;     // 0..56
    const __bf16* Ar = A + (m0 + srow) * lda + scol;
    const __bf16* Br = Bt + (n0 + srow) * ldb + scol;

    f32x4 acc[4][4];
#pragma unroll
    for (int mi = 0; mi < 4; mi++)
#pragma unroll
        for (int ni = 0; ni < 4; ni++) acc[mi][ni] = (f32x4){0.f, 0.f, 0.f, 0.f};

    for (int k0 = 0; k0 < K; k0 += 64) {
        uint4 av[4], bv[4];
#pragma unroll
        for (int p = 0; p < 4; p++) {
            av[p] = *(const uint4*)(Ar + (long)p * 32 * lda + k0);
            bv[p] = *(const uint4*)(Br + (long)p * 32 * ldb + k0);
        }
        __syncthreads();
#pragma unroll
        for (int p = 0; p < 4; p++) {
            *(uint4*)(Asm + (p * 32 + srow) * 64 + scol) = av[p];
            *(uint4*)(Bsm + (p * 32 + srow) * 64 + scol) = bv[p];
        }
        __syncthreads();
#pragma unroll
        for (int ks = 0; ks < 2; ks++) {
            bf16x8 af[4], bfv[4];
#pragma unroll
            for (int mi = 0; mi < 4; mi++)
                af[mi] = *(const bf16x8*)(Asm + (wm * 64 + mi * 16 + l15) * 64 + ks * 32 + l4 * 8);
#pragma unroll
            for (int ni = 0; ni < 4; ni++)
                bfv[ni] = *(const bf16x8*)(Bsm + (wn * 64 + ni * 16 + l15) * 64 + ks * 32 + l4 * 8);
#pragma unroll
            for (int mi = 0; mi < 4; mi++)
#pragma unroll
                for (int ni = 0; ni < 4; ni++)
                    acc[mi][ni] = __builtin_amdgcn_mfma_f32_16x16x32_bf16(af[mi], bfv[ni], acc[mi][ni], 0, 0, 0);
        }
    }

    float* outf = (float*)outp;
    __bf16* outb = (__bf16*)outp;
    const long cOff = (long)blockIdx.z * cBS;
#pragma unroll
    for (int mi = 0; mi < 4; mi++)
#pragma unroll
        for (int ni = 0; ni < 4; ni++) {
            long gmb = m0 + wm * 64 + mi * 16 + l4 * 4;
            long gc  = n0 + wn * 64 + ni * 16 + l15;
#pragma unroll
            for (int i = 0; i < 4; i++) {
                long gm = gmb + i;
                float v = acc[mi][ni][i];
                if (ROWB)  v += rowBias[gm];
                if (COLB)  v += colBias[gc];
                if (GELUF) v = 0.5f * v * (1.f + erff(v * 0.70710678118f));
                if (RES)   v += res[gm * (long)ldres + gc];
                if (OUT == 0)      outf[cOff + gm * (long)ldc + gc] = v;
                else if (OUT == 1) outb[cOff + gm * (long)ldc + gc] = (__bf16)v;
                else               outb[cOff + gc * (long)ldc + gm] = (__bf16)v;
            }
        }
}

// ---------------- fused Linformer attention ----------------
// Q  : bf16 [B*N, 1024]  (head h at col h*64)
// KP : bf16 [B, 256, 1024]
// VPt: bf16 [B, 1024, 256]   (VPt[b][c'][kk])
// O  : bf16 [B*N, 1024]
__global__ __launch_bounds__(256, 2) void attn_fused(
    const __bf16* __restrict__ Q, const __bf16* __restrict__ KP,
    const __bf16* __restrict__ VPt, __bf16* __restrict__ O)
{
    __shared__ __bf16 plds[4][4096];  // per-wave 16x256 bf16 (XOR-swizzled), 8KB each
    const int tid = threadIdx.x, lane = tid & 63, wave = tid >> 6;
    const int l15 = lane & 15, l4 = lane >> 4;
    const int h = blockIdx.y, b = blockIdx.z;
    const long row0 = (long)b * 4096 + (long)blockIdx.x * 64 + wave * 16;

    bf16x8 aq[2];
#pragma unroll
    for (int ks = 0; ks < 2; ks++)
        aq[ks] = *(const bf16x8*)(Q + (row0 + l15) * 1024 + h * 64 + ks * 32 + l4 * 8);

    // scores S[16 x 256] = Q_tile @ KPh^T
    f32x4 s[16];
#pragma unroll
    for (int f = 0; f < 16; f++) {
        f32x4 a = (f32x4){0.f, 0.f, 0.f, 0.f};
#pragma unroll
        for (int ks = 0; ks < 2; ks++) {
            bf16x8 bk = *(const bf16x8*)(KP + ((long)b * 256 + f * 16 + l15) * 1024 + h * 64 + ks * 32 + l4 * 8);
            a = __builtin_amdgcn_mfma_f32_16x16x32_bf16(aq[ks], bk, a, 0, 0, 0);
        }
        s[f] = a;
    }

    // softmax over 256 cols; row r=(l4*4+i) lives in lane-group (same l4), 16 frags
    const float scale = 0.125f;
#pragma unroll
    for (int i = 0; i < 4; i++) {
        float m_ = -3.4e38f;
#pragma unroll
        for (int f = 0; f < 16; f++) { float v = s[f][i] * scale; s[f][i] = v; m_ = fmaxf(m_, v); }
#pragma unroll
        for (int msk = 1; msk < 16; msk <<= 1) m_ = fmaxf(m_, __shfl_xor(m_, msk));
        float su = 0.f;
#pragma unroll
        for (int f = 0; f < 16; f++) { float e = expf(s[f][i] - m_); s[f][i] = e; su += e; }
#pragma unroll
        for (int msk = 1; msk < 16; msk <<= 1) su += __shfl_xor(su, msk);
        float inv = 1.f / su;
#pragma unroll
        for (int f = 0; f < 16; f++) s[f][i] *= inv;
    }

    // write P (bf16) to per-wave LDS with XOR swizzle on 8-elem (16B) units
    __bf16* pl = plds[wave];
#pragma unroll
    for (int f = 0; f < 16; f++)
#pragma unroll
        for (int i = 0; i < 4; i++) {
            int r = l4 * 4 + i, c = f * 16 + l15;
            int off = r * 256 + ((((c >> 3) ^ (r & 7)) << 3) | (c & 7));
            pl[off] = (__bf16)s[f][i];
        }

    // O_tile[16 x 64] = P @ VPh
    f32x4 o[4];
#pragma unroll
    for (int f2 = 0; f2 < 4; f2++) o[f2] = (f32x4){0.f, 0.f, 0.f, 0.f};
#pragma unroll
    for (int ks = 0; ks < 8; ks++) {
        int kk = ks * 32 + l4 * 8;
        int off = l15 * 256 + (((kk >> 3) ^ (l15 & 7)) << 3);
        bf16x8 ap = *(const bf16x8*)(pl + off);
#pragma unroll
        for (int f2 = 0; f2 < 4; f2++) {
            bf16x8 bv = *(const bf16x8*)(VPt + ((long)b * 1024 + h * 64 + f2 * 16 + l15) * 256 + kk);
            o[f2] = __builtin_amdgcn_mfma_f32_16x16x32_bf16(ap, bv, o[f2], 0, 0, 0);
        }
    }
#pragma unroll
    for (int f2 = 0; f2 < 4; f2++)
#pragma unroll
        for (int i = 0; i < 4; i++)
            O[(row0 + l4 * 4 + i) * 1024 + h * 64 + f2 * 16 + l15] = (__bf16)o[f2][i];
}

// ---------------- LayerNorm (row=1024), writes f32 + bf16 ----------------
__global__ __launch_bounds__(256) void ln_kernel(const float* __restrict__ y,
    const float* __restrict__ g, const float* __restrict__ b,
    float* __restrict__ xout, __bf16* __restrict__ xb)
{
    const int row = blockIdx.x;
    const int t = threadIdx.x;
    const float4 v = ((const float4*)(y + (long)row * 1024))[t];
    float s  = v.x + v.y + v.z + v.w;
    float ss = v.x * v.x + v.y * v.y + v.z * v.z + v.w * v.w;
#pragma unroll
    for (int m = 1; m < 64; m <<= 1) { s += __shfl_xor(s, m); ss += __shfl_xor(ss, m); }
    __shared__ float red[2][4];
    const int wave = t >> 6, lane = t & 63;
    if (lane == 0) { red[0][wave] = s; red[1][wave] = ss; }
    __syncthreads();
    s  = red[0][0] + red[0][1] + red[0][2] + red[0][3];
    ss = red[1][0] + red[1][1] + red[1][2] + red[1][3];
    const float mu = s * (1.f / 1024.f);
    const float var = ss * (1.f / 1024.f) - mu * mu;
    const float rs = rsqrtf(var + 1e-5f);
    const float4 gv = ((const float4*)g)[t];
    const float4 bv = ((const float4*)b)[t];
    float o0 = (v.x - mu) * rs * gv.x + bv.x;
    float o1 = (v.y - mu) * rs * gv.y + bv.y;
    float o2 = (v.z - mu) * rs * gv.z + bv.z;
    float o3 = (v.w - mu) * rs * gv.w + bv.w;
    float4 ov; ov.x = o0; ov.y = o1; ov.z = o2; ov.w = o3;
    ((float4*)(xout + (long)row * 1024))[t] = ov;
    __bf16* xr = xb + (long)row * 1024 + t * 4;
    xr[0] = (__bf16)o0; xr[1] = (__bf16)o1; xr[2] = (__bf16)o2; xr[3] = (__bf16)o3;
}

// ---------------- host launch ----------------
extern "C" void kernel_launch(void* const* d_in, const int* in_sizes, int n_in,
                              void* d_out, int out_size, void* d_ws, size_t ws_size,
                              hipStream_t stream) {
    const float* x   = (const float*)d_in[0];
    const float* Wq  = (const float*)d_in[1];
    const float* Wk  = (const float*)d_in[2];
    const float* Wv  = (const float*)d_in[3];
    const float* Wo  = (const float*)d_in[4];
    const float* bo  = (const float*)d_in[5];
    const float* Ew  = (const float*)d_in[6];
    const float* Eb  = (const float*)d_in[7];
    const float* W1  = (const float*)d_in[8];
    const float* b1  = (const float*)d_in[9];
    const float* W2  = (const float*)d_in[10];
    const float* b2  = (const float*)d_in[11];
    const float* lng = (const float*)d_in[12];
    const float* lnb = (const float*)d_in[13];
    float* xout = (float*)d_out;

    // bump allocator on d_ws (all sizes already 256B multiples)
    char* base = (char*)d_ws;
    size_t off = 0;
    auto alloc = [&](size_t bytes) { void* p = base + off; off += (bytes + 255) & ~(size_t)255; return p; };
    __bf16* Wqt = (__bf16*)alloc(2ll * 1024 * 1024 * 2);
    __bf16* Wkt = (__bf16*)alloc(2ll * 1024 * 1024 * 2);
    __bf16* Wvt = (__bf16*)alloc(2ll * 1024 * 1024 * 2);
    __bf16* Wot = (__bf16*)alloc(2ll * 1024 * 1024 * 2);
    __bf16* W1t = (__bf16*)alloc(2ll * 1024 * 4096 * 2);
    __bf16* W2t = (__bf16*)alloc(2ll * 1024 * 4096 * 2);
    __bf16* Ewb = (__bf16*)alloc(256ll * 4096 * 2);
    __bf16* xb  = (__bf16*)alloc(8192ll * 1024 * 2);
    float*  y   = (float*) alloc(8192ll * 1024 * 4);
    __bf16* KPb = (__bf16*)alloc(2ll * 256 * 1024 * 2);
    __bf16* VPt = (__bf16*)alloc(2ll * 1024 * 256 * 2);
    __bf16* Qb  = (__bf16*)alloc(8192ll * 1024 * 2);   // these 4 (64MB) alias FF hidden h
    __bf16* Kt2 = (__bf16*)alloc(1024ll * 8192 * 2);
    __bf16* Vt2 = (__bf16*)alloc(1024ll * 8192 * 2);
    __bf16* Ob  = (__bf16*)alloc(8192ll * 1024 * 2);
    __bf16* hbuf = Qb;  // [8192][4096], reuses Qb..Ob block (dead by FF time)

    // ---- conversions (once per launch) ----
    cvt_f32_bf16<<<2048, 256, 0, stream>>>(x, xb, 8388608);
    cvt_f32_bf16<<<1024, 256, 0, stream>>>(Ew, Ewb, 1048576);
    transpose_cvt<<<dim3(2, 32, 32),  dim3(32, 8), 0, stream>>>(Wq, Wqt, 64, 1024, 65536, 65536);
    transpose_cvt<<<dim3(2, 32, 32),  dim3(32, 8), 0, stream>>>(Wk, Wkt, 64, 1024, 65536, 65536);
    transpose_cvt<<<dim3(2, 32, 32),  dim3(32, 8), 0, stream>>>(Wv, Wvt, 64, 1024, 65536, 65536);
    transpose_cvt<<<dim3(32, 32, 2),  dim3(32, 8), 0, stream>>>(Wo, Wot, 1024, 1024, 1048576, 1048576);
    transpose_cvt<<<dim3(128, 32, 2), dim3(32, 8), 0, stream>>>(W1, W1t, 4096, 1024, 4194304, 4194304);
    transpose_cvt<<<dim3(32, 128, 2), dim3(32, 8), 0, stream>>>(W2, W2t, 1024, 4096, 4194304, 4194304);

    for (int l = 0; l < 2; l++) {
        const __bf16* Wqt_l = Wqt + (long)l * 1048576;
        const __bf16* Wkt_l = Wkt + (long)l * 1048576;
        const __bf16* Wvt_l = Wvt + (long)l * 1048576;
        const __bf16* Wot_l = Wot + (long)l * 1048576;
        const __bf16* W1t_l = W1t + (long)l * 4194304;
        const __bf16* W2t_l = W2t + (long)l * 4194304;
        const float* res = (l == 0) ? x : xout;

        // Q = xb @ Wq^T           -> bf16 [8192,1024]
        gemm_bf16<false, false, false, false, 1><<<dim3(64, 8, 1), 256, 0, stream>>>(
            xb, 1024, 0, Wqt_l, 1024, 0, (void*)Qb, 1024, 0, nullptr, nullptr, nullptr, 0, 1024);
        // K -> transposed bf16 [1024][8192]
        gemm_bf16<false, false, false, false, 2><<<dim3(64, 8, 1), 256, 0, stream>>>(
            xb, 1024, 0, Wkt_l, 1024, 0, (void*)Kt2, 8192, 0, nullptr, nullptr, nullptr, 0, 1024);
        // V -> transposed bf16 [1024][8192]
        gemm_bf16<false, false, false, false, 2><<<dim3(64, 8, 1), 256, 0, stream>>>(
            xb, 1024, 0, Wvt_l, 1024, 0, (void*)Vt2, 8192, 0, nullptr, nullptr, nullptr, 0, 1024);
        // KP[b] = Ew @ K[b] + Eb  -> bf16 [2][256][1024]
        gemm_bf16<true, false, false, false, 1><<<dim3(2, 8, 2), 256, 0, stream>>>(
            Ewb, 4096, 0, Kt2, 8192, 4096, (void*)KPb, 1024, 262144, Eb, nullptr, nullptr, 0, 4096);
        // VP[b] transposed        -> bf16 [2][1024][256]
        gemm_bf16<true, false, false, false, 2><<<dim3(2, 8, 2), 256, 0, stream>>>(
            Ewb, 4096, 0, Vt2, 8192, 4096, (void*)VPt, 256, 262144, Eb, nullptr, nullptr, 0, 4096);
        // fused attention -> O bf16 [8192,1024]
        attn_fused<<<dim3(64, 16, 2), 256, 0, stream>>>(Qb, KPb, VPt, Ob);
        // attn_out = O @ Wo^T + bo + residual -> y f32
        gemm_bf16<false, true, false, true, 0><<<dim3(64, 8, 1), 256, 0, stream>>>(
            Ob, 1024, 0, Wot_l, 1024, 0, (void*)y, 1024, 0, nullptr, bo + l * 1024, res, 1024, 1024);
        ln_kernel<<<8192, 256, 0, stream>>>(y, lng + (2 * l + 0) * 1024, lnb + (2 * l + 0) * 1024, xout, xb);
        // h = gelu(x @ W1 + b1) -> bf16 [8192,4096]
        gemm_bf16<false, true, true, false, 1><<<dim3(64, 32, 1), 256, 0, stream>>>(
            xb, 1024, 0, W1t_l, 1024, 0, (void*)hbuf, 4096, 0, nullptr, b1 + l * 4096, nullptr, 0, 1024);
        // ff = h @ W2 + b2 + residual -> y f32
        gemm_bf16<false, true, false, true, 0><<<dim3(64, 8, 1), 256, 0, stream>>>(
            hbuf, 4096, 0, W2t_l, 4096, 0, (void*)y, 1024, 0, nullptr, b2 + l * 1024, xout, 1024, 4096);
        ln_kernel<<<8192, 256, 0, stream>>>(y, lng + (2 * l + 1) * 1024, lnb + (2 * l + 1) * 1024, xout, xb);
    }
}

// Round 2
// 978.777 us; speedup vs baseline: 3.2102x; 3.2102x over previous
//
#include <hip/hip_runtime.h>
#include <hip/hip_bf16.h>
#include <math.h>

// ---------------- types ----------------
typedef __bf16 bf16x8 __attribute__((ext_vector_type(8)));
typedef float f32x4 __attribute__((ext_vector_type(4)));

// ---------------- conversion kernels ----------------
__global__ void cvt_f32_bf16(const float* __restrict__ in, __bf16* __restrict__ out, long n) {
    long i = ((long)blockIdx.x * 256 + threadIdx.x) * 4;
    long stride = (long)gridDim.x * 1024;
    for (; i < n; i += stride) {
        float4 v = *(const float4*)(in + i);
        out[i + 0] = (__bf16)v.x;
        out[i + 1] = (__bf16)v.y;
        out[i + 2] = (__bf16)v.z;
        out[i + 3] = (__bf16)v.w;
    }
}

// transpose + convert: in f32 [M][N] (ldin) -> out bf16 [N][M] (ldout), batched over z
__global__ void transpose_cvt(const float* __restrict__ in, __bf16* __restrict__ out,
                              int ldin, int ldout, long inBS, long outBS) {
    __shared__ __bf16 tile[32][33];
    in  += (long)blockIdx.z * inBS;
    out += (long)blockIdx.z * outBS;
    int n0 = blockIdx.x * 32, m0 = blockIdx.y * 32;
    for (int i = threadIdx.y; i < 32; i += 8)
        tile[i][threadIdx.x] = (__bf16)in[(long)(m0 + i) * ldin + n0 + threadIdx.x];
    __syncthreads();
    for (int i = threadIdx.y; i < 32; i += 8)
        out[(long)(n0 + i) * ldout + m0 + threadIdx.x] = tile[threadIdx.x][i];
}

// bf16 transpose: in [rows][cols] -> out [cols][rows], batched over z (batch stride rows*cols)
__global__ void transpose_bf16(const __bf16* __restrict__ in, __bf16* __restrict__ out,
                               int rows, int cols) {
    __shared__ __bf16 tile[32][33];
    in  += (long)blockIdx.z * rows * cols;
    out += (long)blockIdx.z * rows * cols;
    int c0 = blockIdx.x * 32, r0 = blockIdx.y * 32;
    for (int i = threadIdx.y; i < 32; i += 8)
        tile[i][threadIdx.x] = in[(long)(r0 + i) * cols + c0 + threadIdx.x];
    __syncthreads();
    for (int i = threadIdx.y; i < 32; i += 8)
        out[(long)(c0 + i) * rows + r0 + threadIdx.x] = tile[threadIdx.x][i];
}

// ---------------- GEMM: C[M,N] = A[M,K] @ Bt[N,K]^T (+epilogue) ----------------
// global_load_lds staging (width 16) with T2 XOR swizzle via pre-swizzled global source.
// OUT: 0 = f32 normal, 1 = bf16 normal, 2 = bf16 transposed (out[n*ldc + m])
template<bool ROWB, bool COLB, bool GELUF, bool RES, int OUT>
__global__ __launch_bounds__(256, 2) void gemm_bf16(
    const __bf16* __restrict__ A, int lda, long aBS,
    const __bf16* __restrict__ Bt, int ldb, long bBS,
    void* __restrict__ outp, int ldc, long cBS,
    const float* __restrict__ rowBias,
    const float* __restrict__ colBias,
    const float* __restrict__ res, int ldres,
    int K)
{
    __shared__ __bf16 Asm[128 * 64];
    __shared__ __bf16 Bsm[128 * 64];
    const int tid = threadIdx.x;
    const int lane = tid & 63, wave = tid >> 6;
    const int wm = wave >> 1, wn = wave & 1;
    const int l15 = lane & 15, l4 = lane >> 4;

    // XCD-aware block swizzle (bijective: all our grids have nwg % 8 == 0)
    int bx = blockIdx.x, by = blockIdx.y;
    {
        int nwg = gridDim.x * gridDim.y;
        if ((nwg & 7) == 0) {
            int id = by * gridDim.x + bx;
            int cpx = nwg >> 3;
            int swz = (id & 7) * cpx + (id >> 3);
            bx = swz % gridDim.x;
            by = swz / gridDim.x;
        }
    }
    const long m0 = (long)bx * 128, n0 = (long)by * 128;
    A  += (long)blockIdx.z * aBS;
    Bt += (long)blockIdx.z * bBS;

    // staging: wave w, round p covers LDS rows p*32 + w*8 .. +8 (linear dest).
    // lane l -> row += l>>3, 16B unit = l&7. Pre-swizzle the GLOBAL unit so that
    // LDS unit u of row r holds global unit u ^ (r&7).
    const int srow8 = lane >> 3;                 // 0..7
    const int gunit = ((lane & 7) ^ srow8) << 3; // element col offset in k-tile
    const __bf16* Abase = A  + (m0 + wave * 8 + srow8) * (long)lda + gunit;
    const __bf16* Bbase = Bt + (n0 + wave * 8 + srow8) * (long)ldb + gunit;
    __bf16* AsmW = Asm + wave * 8 * 64;
    __bf16* BsmW = Bsm + wave * 8 * 64;
    const int swz_r = l15 & 7;                   // ds_read row-swizzle key

    f32x4 acc[4][4];
#pragma unroll
    for (int mi = 0; mi < 4; mi++)
#pragma unroll
        for (int ni = 0; ni < 4; ni++) acc[mi][ni] = (f32x4){0.f, 0.f, 0.f, 0.f};

    for (int k0 = 0; k0 < K; k0 += 64) {
        __syncthreads();  // previous tile's reads complete before overwrite
#pragma unroll
        for (int p = 0; p < 4; p++) {
            __builtin_amdgcn_global_load_lds(
                (const __attribute__((address_space(1))) unsigned int*)(Abase + (long)p * 32 * lda + k0),
                (__attribute__((address_space(3))) unsigned int*)(AsmW + p * 32 * 64), 16, 0, 0);
            __builtin_amdgcn_global_load_lds(
                (const __attribute__((address_space(1))) unsigned int*)(Bbase + (long)p * 32 * ldb + k0),
                (__attribute__((address_space(3))) unsigned int*)(BsmW + p * 32 * 64), 16, 0, 0);
        }
        asm volatile("s_waitcnt vmcnt(0)" ::: "memory");
        __syncthreads();
#pragma unroll
        for (int ks = 0; ks < 2; ks++) {
            bf16x8 af[4], bfv[4];
#pragma unroll
            for (int mi = 0; mi < 4; mi++)
                af[mi] = *(const bf16x8*)(Asm + (wm * 64 + mi * 16 + l15) * 64 + (((ks * 4 + l4) ^ swz_r) << 3));
#pragma unroll
            for (int ni = 0; ni < 4; ni++)
                bfv[ni] = *(const bf16x8*)(Bsm + (wn * 64 + ni * 16 + l15) * 64 + (((ks * 4 + l4) ^ swz_r) << 3));
#pragma unroll
            for (int mi = 0; mi < 4; mi++)
#pragma unroll
                for (int ni = 0; ni < 4; ni++)
                    acc[mi][ni] = __builtin_amdgcn_mfma_f32_16x16x32_bf16(af[mi], bfv[ni], acc[mi][ni], 0, 0, 0);
        }
    }

    float* outf = (float*)outp;
    __bf16* outb = (__bf16*)outp;
    const long cOff = (long)blockIdx.z * cBS;
#pragma unroll
    for (int mi = 0; mi < 4; mi++)
#pragma unroll
        for (int ni = 0; ni < 4; ni++) {
            long gmb = m0 + wm * 64 + mi * 16 + l4 * 4;
            long gc  = n0 + wn * 64 + ni * 16 + l15;
#pragma unroll
            for (int i = 0; i < 4; i++) {
                long gm = gmb + i;
                float v = acc[mi][ni][i];
                if (ROWB)  v += rowBias[gm];
                if (COLB)  v += colBias[gc];
                if (GELUF) v = 0.5f * v * (1.f + erff(v * 0.70710678118f));
                if (RES)   v += res[gm * (long)ldres + gc];
                if (OUT == 0)      outf[cOff + gm * (long)ldc + gc] = v;
                else if (OUT == 1) outb[cOff + gm * (long)ldc + gc] = (__bf16)v;
                else               outb[cOff + gc * (long)ldc + gm] = (__bf16)v;
            }
        }
}

// ---------------- fused Linformer attention ----------------
// Q  : bf16 [B*N, 1024]  (head h at col h*64)
// KP : bf16 [B, 256, 1024]
// VPt: bf16 [B, 1024, 256]   (VPt[b][c'][kk])
// O  : bf16 [B*N, 1024]
__global__ __launch_bounds__(256, 2) void attn_fused(
    const __bf16* __restrict__ Q, const __bf16* __restrict__ KP,
    const __bf16* __restrict__ VPt, __bf16* __restrict__ O)
{
    __shared__ __bf16 plds[4][4096];  // per-wave 16x256 bf16 (XOR-swizzled), 8KB each
    const int tid = threadIdx.x, lane = tid & 63, wave = tid >> 6;
    const int l15 = lane & 15, l4 = lane >> 4;
    const int h = blockIdx.y, b = blockIdx.z;
    const long row0 = (long)b * 4096 + (long)blockIdx.x * 64 + wave * 16;

    bf16x8 aq[2];
#pragma unroll
    for (int ks = 0; ks < 2; ks++)
        aq[ks] = *(const bf16x8*)(Q + (row0 + l15) * 1024 + h * 64 + ks * 32 + l4 * 8);

    // scores S[16 x 256] = Q_tile @ KPh^T
    f32x4 s[16];
#pragma unroll
    for (int f = 0; f < 16; f++) {
        f32x4 a = (f32x4){0.f, 0.f, 0.f, 0.f};
#pragma unroll
        for (int ks = 0; ks < 2; ks++) {
            bf16x8 bk = *(const bf16x8*)(KP + ((long)b * 256 + f * 16 + l15) * 1024 + h * 64 + ks * 32 + l4 * 8);
            a = __builtin_amdgcn_mfma_f32_16x16x32_bf16(aq[ks], bk, a, 0, 0, 0);
        }
        s[f] = a;
    }

    // softmax over 256 cols; row r=(l4*4+i) lives across the 16-lane group
    const float scale = 0.125f;
#pragma unroll
    for (int i = 0; i < 4; i++) {
        float m_ = -3.4e38f;
#pragma unroll
        for (int f = 0; f < 16; f++) { float v = s[f][i] * scale; s[f][i] = v; m_ = fmaxf(m_, v); }
#pragma unroll
        for (int msk = 1; msk < 16; msk <<= 1) m_ = fmaxf(m_, __shfl_xor(m_, msk));
        float su = 0.f;
#pragma unroll
        for (int f = 0; f < 16; f++) { float e = expf(s[f][i] - m_); s[f][i] = e; su += e; }
#pragma unroll
        for (int msk = 1; msk < 16; msk <<= 1) su += __shfl_xor(su, msk);
        float inv = 1.f / su;
#pragma unroll
        for (int f = 0; f < 16; f++) s[f][i] *= inv;
    }

    // write P (bf16) to per-wave LDS with XOR swizzle on 8-elem (16B) units
    __bf16* pl = plds[wave];
#pragma unroll
    for (int f = 0; f < 16; f++)
#pragma unroll
        for (int i = 0; i < 4; i++) {
            int r = l4 * 4 + i, c = f * 16 + l15;
            int off = r * 256 + ((((c >> 3) ^ (r & 7)) << 3) | (c & 7));
            pl[off] = (__bf16)s[f][i];
        }

    // O_tile[16 x 64] = P @ VPh
    f32x4 o[4];
#pragma unroll
    for (int f2 = 0; f2 < 4; f2++) o[f2] = (f32x4){0.f, 0.f, 0.f, 0.f};
#pragma unroll
    for (int ks = 0; ks < 8; ks++) {
        int kk = ks * 32 + l4 * 8;
        int off = l15 * 256 + (((kk >> 3) ^ (l15 & 7)) << 3);
        bf16x8 ap = *(const bf16x8*)(pl + off);
#pragma unroll
        for (int f2 = 0; f2 < 4; f2++) {
            bf16x8 bv = *(const bf16x8*)(VPt + ((long)b * 1024 + h * 64 + f2 * 16 + l15) * 256 + kk);
            o[f2] = __builtin_amdgcn_mfma_f32_16x16x32_bf16(ap, bv, o[f2], 0, 0, 0);
        }
    }
#pragma unroll
    for (int f2 = 0; f2 < 4; f2++)
#pragma unroll
        for (int i = 0; i < 4; i++)
            O[(row0 + l4 * 4 + i) * 1024 + h * 64 + f2 * 16 + l15] = (__bf16)o[f2][i];
}

// ---------------- LayerNorm (row=1024), writes f32 + bf16 ----------------
__global__ __launch_bounds__(256) void ln_kernel(const float* __restrict__ y,
    const float* __restrict__ g, const float* __restrict__ b,
    float* __restrict__ xout, __bf16* __restrict__ xb)
{
    const int row = blockIdx.x;
    const int t = threadIdx.x;
    const float4 v = ((const float4*)(y + (long)row * 1024))[t];
    float s  = v.x + v.y + v.z + v.w;
    float ss = v.x * v.x + v.y * v.y + v.z * v.z + v.w * v.w;
#pragma unroll
    for (int m = 1; m < 64; m <<= 1) { s += __shfl_xor(s, m); ss += __shfl_xor(ss, m); }
    __shared__ float red[2][4];
    const int wave = t >> 6, lane = t & 63;
    if (lane == 0) { red[0][wave] = s; red[1][wave] = ss; }
    __syncthreads();
    s  = red[0][0] + red[0][1] + red[0][2] + red[0][3];
    ss = red[1][0] + red[1][1] + red[1][2] + red[1][3];
    const float mu = s * (1.f / 1024.f);
    const float var = ss * (1.f / 1024.f) - mu * mu;
    const float rs = rsqrtf(var + 1e-5f);
    const float4 gv = ((const float4*)g)[t];
    const float4 bv = ((const float4*)b)[t];
    float o0 = (v.x - mu) * rs * gv.x + bv.x;
    float o1 = (v.y - mu) * rs * gv.y + bv.y;
    float o2 = (v.z - mu) * rs * gv.z + bv.z;
    float o3 = (v.w - mu) * rs * gv.w + bv.w;
    float4 ov; ov.x = o0; ov.y = o1; ov.z = o2; ov.w = o3;
    ((float4*)(xout + (long)row * 1024))[t] = ov;
    __bf16* xr = xb + (long)row * 1024 + t * 4;
    xr[0] = (__bf16)o0; xr[1] = (__bf16)o1; xr[2] = (__bf16)o2; xr[3] = (__bf16)o3;
}

// ---------------- host launch ----------------
extern "C" void kernel_launch(void* const* d_in, const int* in_sizes, int n_in,
                              void* d_out, int out_size, void* d_ws, size_t ws_size,
                              hipStream_t stream) {
    const float* x   = (const float*)d_in[0];
    const float* Wq  = (const float*)d_in[1];
    const float* Wk  = (const float*)d_in[2];
    const float* Wv  = (const float*)d_in[3];
    const float* Wo  = (const float*)d_in[4];
    const float* bo  = (const float*)d_in[5];
    const float* Ew  = (const float*)d_in[6];
    const float* Eb  = (const float*)d_in[7];
    const float* W1  = (const float*)d_in[8];
    const float* b1  = (const float*)d_in[9];
    const float* W2  = (const float*)d_in[10];
    const float* b2  = (const float*)d_in[11];
    const float* lng = (const float*)d_in[12];
    const float* lnb = (const float*)d_in[13];
    float* xout = (float*)d_out;

    // bump allocator on d_ws
    char* base = (char*)d_ws;
    size_t off = 0;
    auto alloc = [&](size_t bytes) { void* p = base + off; off += (bytes + 255) & ~(size_t)255; return p; };
    __bf16* Wqt = (__bf16*)alloc(2ll * 1024 * 1024 * 2);
    __bf16* Wkt = (__bf16*)alloc(2ll * 1024 * 1024 * 2);
    __bf16* Wvt = (__bf16*)alloc(2ll * 1024 * 1024 * 2);
    __bf16* Wot = (__bf16*)alloc(2ll * 1024 * 1024 * 2);
    __bf16* W1t = (__bf16*)alloc(2ll * 1024 * 4096 * 2);
    __bf16* W2t = (__bf16*)alloc(2ll * 1024 * 4096 * 2);
    __bf16* Ewb = (__bf16*)alloc(256ll * 4096 * 2);
    __bf16* xb  = (__bf16*)alloc(8192ll * 1024 * 2);
    __bf16* xbT = (__bf16*)alloc(2ll * 1024 * 4096 * 2);
    float*  y   = (float*) alloc(8192ll * 1024 * 4);
    __bf16* xp  = (__bf16*)alloc(2ll * 256 * 1024 * 2);
    __bf16* KPb = (__bf16*)alloc(2ll * 256 * 1024 * 2);
    __bf16* VPt = (__bf16*)alloc(2ll * 1024 * 256 * 2);
    __bf16* big = (__bf16*)alloc(8192ll * 4096 * 2);   // 64 MB region
    __bf16* Qb  = big;                                  // [8192][1024]
    __bf16* Ob  = big + 8192ll * 2048;                  // [8192][1024]
    __bf16* hbuf = big;                                 // [8192][4096], after Qb/Ob dead

    // ---- conversions (once per launch) ----
    cvt_f32_bf16<<<2048, 256, 0, stream>>>(x, xb, 8388608);
    cvt_f32_bf16<<<1024, 256, 0, stream>>>(Ew, Ewb, 1048576);
    transpose_cvt<<<dim3(2, 32, 32),  dim3(32, 8), 0, stream>>>(Wq, Wqt, 64, 1024, 65536, 65536);
    transpose_cvt<<<dim3(2, 32, 32),  dim3(32, 8), 0, stream>>>(Wk, Wkt, 64, 1024, 65536, 65536);
    transpose_cvt<<<dim3(2, 32, 32),  dim3(32, 8), 0, stream>>>(Wv, Wvt, 64, 1024, 65536, 65536);
    transpose_cvt<<<dim3(32, 32, 2),  dim3(32, 8), 0, stream>>>(Wo, Wot, 1024, 1024, 1048576, 1048576);
    transpose_cvt<<<dim3(128, 32, 2), dim3(32, 8), 0, stream>>>(W1, W1t, 4096, 1024, 4194304, 4194304);
    transpose_cvt<<<dim3(32, 128, 2), dim3(32, 8), 0, stream>>>(W2, W2t, 1024, 4096, 4194304, 4194304);

    for (int l = 0; l < 2; l++) {
        const __bf16* Wqt_l = Wqt + (long)l * 1048576;
        const __bf16* Wkt_l = Wkt + (long)l * 1048576;
        const __bf16* Wvt_l = Wvt + (long)l * 1048576;
        const __bf16* Wot_l = Wot + (long)l * 1048576;
        const __bf16* W1t_l = W1t + (long)l * 4194304;
        const __bf16* W2t_l = W2t + (long)l * 4194304;
        const float* res = (l == 0) ? x : xout;

        // xbT[b] = xb[b]^T  (per batch [4096][1024] -> [1024][4096])
        transpose_bf16<<<dim3(32, 128, 2), dim3(32, 8), 0, stream>>>(xb, xbT, 4096, 1024);
        // xp[b] = Ew @ x[b]   : A=Ewb [256][4096], Bt=xbT [1024][4096] -> [2][256][1024]
        gemm_bf16<false, false, false, false, 1><<<dim3(2, 8, 2), 256, 0, stream>>>(
            Ewb, 4096, 0, xbT, 4096, 4194304, (void*)xp, 1024, 262144,
            nullptr, nullptr, nullptr, 0, 4096);
        // Q = xb @ Wq^T -> bf16 [8192,1024]
        gemm_bf16<false, false, false, false, 1><<<dim3(64, 8, 1), 256, 0, stream>>>(
            xb, 1024, 0, Wqt_l, 1024, 0, (void*)Qb, 1024, 0, nullptr, nullptr, nullptr, 0, 1024);
        // KP[b] = xp[b] @ Wk^T + Eb -> bf16 [2][256][1024]
        gemm_bf16<true, false, false, false, 1><<<dim3(2, 8, 2), 256, 0, stream>>>(
            xp, 1024, 262144, Wkt_l, 1024, 0, (void*)KPb, 1024, 262144,
            Eb, nullptr, nullptr, 0, 1024);
        // VPt[b] = (xp[b] @ Wv^T + Eb)^T -> bf16 [2][1024][256]
        gemm_bf16<true, false, false, false, 2><<<dim3(2, 8, 2), 256, 0, stream>>>(
            xp, 1024, 262144, Wvt_l, 1024, 0, (void*)VPt, 256, 262144,
            Eb, nullptr, nullptr, 0, 1024);
        // fused attention -> O bf16 [8192,1024]
        attn_fused<<<dim3(64, 16, 2), 256, 0, stream>>>(Qb, KPb, VPt, Ob);
        // attn_out = O @ Wo^T + bo + residual -> y f32
        gemm_bf16<false, true, false, true, 0><<<dim3(64, 8, 1), 256, 0, stream>>>(
            Ob, 1024, 0, Wot_l, 1024, 0, (void*)y, 1024, 0,
            nullptr, bo + l * 1024, res, 1024, 1024);
        ln_kernel<<<8192, 256, 0, stream>>>(y, lng + (2 * l + 0) * 1024, lnb + (2 * l + 0) * 1024, xout, xb);
        // h = gelu(x @ W1 + b1) -> bf16 [8192,4096]
        gemm_bf16<false, true, true, false, 1><<<dim3(64, 32, 1), 256, 0, stream>>>(
            xb, 1024, 0, W1t_l, 1024, 0, (void*)hbuf, 4096, 0,
            nullptr, b1 + l * 4096, nullptr, 0, 1024);
        // ff = h @ W2 + b2 + residual -> y f32
        gemm_bf16<false, true, false, true, 0><<<dim3(64, 8, 1), 256, 0, stream>>>(
            hbuf, 4096, 0, W2t_l, 4096, 0, (void*)y, 1024, 0,
            nullptr, b2 + l * 1024, xout, 1024, 4096);
        ln_kernel<<<8192, 256, 0, stream>>>(y, lng + (2 * l + 1) * 1024, lnb + (2 * l + 1) * 1024, xout, xb);
    }
}

// Round 3
// 964.653 us; speedup vs baseline: 3.2572x; 1.0146x over previous
//
#include <hip/hip_runtime.h>
#include <hip/hip_bf16.h>
#include <math.h>

// ---------------- types ----------------
typedef __bf16 bf16x8 __attribute__((ext_vector_type(8)));
typedef float f32x4 __attribute__((ext_vector_type(4)));

// ---------------- conversion kernels ----------------
__global__ void cvt_f32_bf16(const float* __restrict__ in, __bf16* __restrict__ out, long n) {
    long i = ((long)blockIdx.x * 256 + threadIdx.x) * 4;
    long stride = (long)gridDim.x * 1024;
    for (; i < n; i += stride) {
        float4 v = *(const float4*)(in + i);
        out[i + 0] = (__bf16)v.x;
        out[i + 1] = (__bf16)v.y;
        out[i + 2] = (__bf16)v.z;
        out[i + 3] = (__bf16)v.w;
    }
}

// transpose + convert: in f32 [M][N] (ldin) -> out bf16 [N][M] (ldout), batched over z
__global__ void transpose_cvt(const float* __restrict__ in, __bf16* __restrict__ out,
                              int ldin, int ldout, long inBS, long outBS) {
    __shared__ __bf16 tile[32][33];
    in  += (long)blockIdx.z * inBS;
    out += (long)blockIdx.z * outBS;
    int n0 = blockIdx.x * 32, m0 = blockIdx.y * 32;
    for (int i = threadIdx.y; i < 32; i += 8)
        tile[i][threadIdx.x] = (__bf16)in[(long)(m0 + i) * ldin + n0 + threadIdx.x];
    __syncthreads();
    for (int i = threadIdx.y; i < 32; i += 8)
        out[(long)(n0 + i) * ldout + m0 + threadIdx.x] = tile[threadIdx.x][i];
}

// bf16 transpose: in [rows][cols] -> out [cols][rows], batched over z
__global__ void transpose_bf16(const __bf16* __restrict__ in, __bf16* __restrict__ out,
                               int rows, int cols) {
    __shared__ __bf16 tile[32][33];
    in  += (long)blockIdx.z * rows * cols;
    out += (long)blockIdx.z * rows * cols;
    int c0 = blockIdx.x * 32, r0 = blockIdx.y * 32;
    for (int i = threadIdx.y; i < 32; i += 8)
        tile[i][threadIdx.x] = in[(long)(r0 + i) * cols + c0 + threadIdx.x];
    __syncthreads();
    for (int i = threadIdx.y; i < 32; i += 8)
        out[(long)(c0 + i) * rows + r0 + threadIdx.x] = tile[threadIdx.x][i];
}

// ================= gemm256: 256xBN tile, BK=64, 8 waves, 2-slab phased =================
// C[M,N] = A[M,K] @ Bt[N,K]^T (+epilogue). K%64==0, K>=128. Grid (M/256, N/BN), 512 thr.
// OUT: 0 = f32, 1 = bf16
template<int BN, int WM, int WN, bool ROWB, bool COLB, bool GELUF, bool RES, int OUT>
__global__ __launch_bounds__(512, 2) void gemm256(
    const __bf16* __restrict__ A, int lda,
    const __bf16* __restrict__ Bt, int ldb,
    void* __restrict__ outp, int ldc,
    const float* __restrict__ rowBias,
    const float* __restrict__ colBias,
    const float* __restrict__ res, int ldres,
    int K)
{
    constexpr int M_REP = 256 / WM / 16;
    constexpr int N_REP = BN / WN / 16;
    constexpr int A_SLAB = 256 * 32;       // elems per A k-slab
    constexpr int B_SLAB = BN * 32;
    constexpr int A_ISS = 2;               // global_load_lds issues per wave per A-slab
    constexpr int B_ISS = BN / 128;        // 2 (BN=256) or 1 (BN=128)
    constexpr int LPS = A_ISS + B_ISS;     // loads per slab per wave

    __shared__ __bf16 Asm[2 * 2 * A_SLAB];
    __shared__ __bf16 Bsm[2 * 2 * B_SLAB];

    const int tid = threadIdx.x;
    const int lane = tid & 63, wave = tid >> 6;
    const int l15 = lane & 15, l4 = lane >> 4;
    const int wm = wave / WN, wn = wave % WN;

    // XCD-grouped swizzle: XCD k owns M-panels [k*px, (k+1)*px) x all N columns
    int bx, by;
    {
        int orig = blockIdx.y * gridDim.x + blockIdx.x;
        int xcd = orig & 7, local = orig >> 3;
        int px = gridDim.x >> 3;
        bx = xcd * px + (local % px);
        by = local / px;
    }
    const long m0 = (long)bx * 256, n0 = (long)by * BN;

    // staging lane geometry (global source pre-swizzled; LDS dest linear)
    const int srow = lane >> 2;                                  // 0..15
    const int scol = (((lane & 3) ^ ((lane >> 3) & 3)) << 3);    // elems
    const int arow = wave * 32 + srow;
    const int brow = wave * (BN / 8) + srow;

    // ds_read swizzled offsets (elems); row stride 32 elems (64B)
    const int swzr = (l15 >> 1) & 3;
    const int offA = (wm * (256 / WM) + l15) * 32 + ((l4 ^ swzr) << 3);
    const int offB = (wn * (BN / WN) + l15) * 32 + ((l4 ^ swzr) << 3);

    f32x4 acc[M_REP][N_REP];
#pragma unroll
    for (int mi = 0; mi < M_REP; mi++)
#pragma unroll
        for (int ni = 0; ni < N_REP; ni++) acc[mi][ni] = (f32x4){0.f, 0.f, 0.f, 0.f};

    auto stage = [&](int buf, int slab, int t) {
        const __bf16* as = A + (m0 + arow) * (long)lda + (long)t * 64 + slab * 32 + scol;
        __bf16* ad = Asm + (buf * 2 + slab) * A_SLAB + wave * 1024;
#pragma unroll
        for (int j = 0; j < A_ISS; j++)
            __builtin_amdgcn_global_load_lds(
                (const __attribute__((address_space(1))) unsigned int*)(as + (long)j * 16 * lda),
                (__attribute__((address_space(3))) unsigned int*)(ad + j * 512), 16, 0, 0);
        const __bf16* bs = Bt + (n0 + brow) * (long)ldb + (long)t * 64 + slab * 32 + scol;
        __bf16* bd = Bsm + (buf * 2 + slab) * B_SLAB + wave * (BN / 8 * 32);
#pragma unroll
        for (int j = 0; j < B_ISS; j++)
            __builtin_amdgcn_global_load_lds(
                (const __attribute__((address_space(1))) unsigned int*)(bs + (long)j * 16 * ldb),
                (__attribute__((address_space(3))) unsigned int*)(bd + j * 512), 16, 0, 0);
    };

    auto compute = [&](int buf, int slab) {
        const __bf16* Ab = Asm + (buf * 2 + slab) * A_SLAB;
        const __bf16* Bb = Bsm + (buf * 2 + slab) * B_SLAB;
        bf16x8 af[M_REP], bfv[N_REP];
#pragma unroll
        for (int mi = 0; mi < M_REP; mi++) af[mi] = *(const bf16x8*)(Ab + offA + mi * 512);
#pragma unroll
        for (int ni = 0; ni < N_REP; ni++) bfv[ni] = *(const bf16x8*)(Bb + offB + ni * 512);
        __builtin_amdgcn_s_setprio(1);
#pragma unroll
        for (int mi = 0; mi < M_REP; mi++)
#pragma unroll
            for (int ni = 0; ni < N_REP; ni++)
                acc[mi][ni] = __builtin_amdgcn_mfma_f32_16x16x32_bf16(af[mi], bfv[ni], acc[mi][ni], 0, 0, 0);
        __builtin_amdgcn_s_setprio(0);
    };

    const int NT = K >> 6;  // >= 2
    stage(0, 0, 0);
    stage(0, 1, 0);
    stage(1, 0, 1);

    for (int t = 0; t < NT; t++) {
        const int buf = t & 1;
        // ---- phase 0: consume slab0(t), prefetch slab1(t+1) ----
        if (t < NT - 1) { asm volatile("s_waitcnt vmcnt(%0)" :: "i"(2 * LPS) : "memory"); }
        else            { asm volatile("s_waitcnt vmcnt(%0)" :: "i"(LPS) : "memory"); }
        __builtin_amdgcn_s_barrier();
        __builtin_amdgcn_sched_barrier(0);
        if (t + 1 < NT) stage(buf ^ 1, 1, t + 1);
        compute(buf, 0);
        // ---- phase 1: consume slab1(t), prefetch slab0(t+2) ----
        if (t < NT - 1) { asm volatile("s_waitcnt vmcnt(%0)" :: "i"(2 * LPS) : "memory"); }
        else            { asm volatile("s_waitcnt vmcnt(0)" ::: "memory"); }
        __builtin_amdgcn_s_barrier();
        __builtin_amdgcn_sched_barrier(0);
        if (t + 2 < NT) stage(buf, 0, t + 2);
        compute(buf, 1);
    }

    float* outf = (float*)outp;
    __bf16* outb = (__bf16*)outp;
#pragma unroll
    for (int mi = 0; mi < M_REP; mi++)
#pragma unroll
        for (int ni = 0; ni < N_REP; ni++) {
            long gmb = m0 + wm * (256 / WM) + mi * 16 + l4 * 4;
            long gc  = n0 + wn * (BN / WN) + ni * 16 + l15;
#pragma unroll
            for (int i = 0; i < 4; i++) {
                long gm = gmb + i;
                float v = acc[mi][ni][i];
                if (ROWB)  v += rowBias[gm];
                if (COLB)  v += colBias[gc];
                if (GELUF) v = 0.5f * v * (1.f + erff(v * 0.70710678118f));
                if (RES)   v += res[gm * (long)ldres + gc];
                if (OUT == 0) outf[gm * (long)ldc + gc] = v;
                else          outb[gm * (long)ldc + gc] = (__bf16)v;
            }
        }
}

// ========== gemm128_split: 128x128 tile split-K, writes f32 partials ==========
// z = batch*S + s ; partial P[z][M][N] (stride cBS)
__global__ __launch_bounds__(256, 2) void gemm128_split(
    const __bf16* __restrict__ A, int lda, long aBS,
    const __bf16* __restrict__ Bt, int ldb, long bBS,
    float* __restrict__ P, long cBS, int ldc,
    int Ksplit, int S)
{
    __shared__ __bf16 Asm[128 * 64];
    __shared__ __bf16 Bsm[128 * 64];
    const int tid = threadIdx.x;
    const int lane = tid & 63, wave = tid >> 6;
    const int wm = wave >> 1, wn = wave & 1;
    const int l15 = lane & 15, l4 = lane >> 4;
    const long m0 = (long)blockIdx.x * 128, n0 = (long)blockIdx.y * 128;
    const long zb = blockIdx.z / S;
    const int  sp = blockIdx.z % S;
    A  += zb * aBS + (long)sp * Ksplit;
    Bt += zb * bBS + (long)sp * Ksplit;

    const int srow8 = lane >> 3;
    const int gunit = ((lane & 7) ^ srow8) << 3;
    const __bf16* Abase = A + (m0 + wave * 8 + srow8) * (long)lda + gunit;
    const __bf16* Bbase = Bt + (n0 + wave * 8 + srow8) * (long)ldb + gunit;
    __bf16* AsmW = Asm + wave * 8 * 64;
    __bf16* BsmW = Bsm + wave * 8 * 64;
    const int swz_r = l15 & 7;

    f32x4 acc[4][4];
#pragma unroll
    for (int mi = 0; mi < 4; mi++)
#pragma unroll
        for (int ni = 0; ni < 4; ni++) acc[mi][ni] = (f32x4){0.f, 0.f, 0.f, 0.f};

    for (int k0 = 0; k0 < Ksplit; k0 += 64) {
        __syncthreads();
#pragma unroll
        for (int p = 0; p < 4; p++) {
            __builtin_amdgcn_global_load_lds(
                (const __attribute__((address_space(1))) unsigned int*)(Abase + (long)p * 32 * lda + k0),
                (__attribute__((address_space(3))) unsigned int*)(AsmW + p * 32 * 64), 16, 0, 0);
            __builtin_amdgcn_global_load_lds(
                (const __attribute__((address_space(1))) unsigned int*)(Bbase + (long)p * 32 * ldb + k0),
                (__attribute__((address_space(3))) unsigned int*)(BsmW + p * 32 * 64), 16, 0, 0);
        }
        asm volatile("s_waitcnt vmcnt(0)" ::: "memory");
        __syncthreads();
#pragma unroll
        for (int ks = 0; ks < 2; ks++) {
            bf16x8 af[4], bfv[4];
#pragma unroll
            for (int mi = 0; mi < 4; mi++)
                af[mi] = *(const bf16x8*)(Asm + (wm * 64 + mi * 16 + l15) * 64 + (((ks * 4 + l4) ^ swz_r) << 3));
#pragma unroll
            for (int ni = 0; ni < 4; ni++)
                bfv[ni] = *(const bf16x8*)(Bsm + (wn * 64 + ni * 16 + l15) * 64 + (((ks * 4 + l4) ^ swz_r) << 3));
#pragma unroll
            for (int mi = 0; mi < 4; mi++)
#pragma unroll
                for (int ni = 0; ni < 4; ni++)
                    acc[mi][ni] = __builtin_amdgcn_mfma_f32_16x16x32_bf16(af[mi], bfv[ni], acc[mi][ni], 0, 0, 0);
        }
    }

    float* out = P + (long)blockIdx.z * cBS;
#pragma unroll
    for (int mi = 0; mi < 4; mi++)
#pragma unroll
        for (int ni = 0; ni < 4; ni++) {
            long gmb = m0 + wm * 64 + mi * 16 + l4 * 4;
            long gc  = n0 + wn * 64 + ni * 16 + l15;
#pragma unroll
            for (int i = 0; i < 4; i++)
                out[(gmb + i) * (long)ldc + gc] = acc[mi][ni][i];
        }
}

// ---------- reduce S f32 partials -> bf16 (+row bias, optional transposed write) ----------
template<bool BIAS, bool TRANS>
__global__ __launch_bounds__(256) void reduce_partials(
    const float* __restrict__ P, __bf16* __restrict__ out,
    const float* __restrict__ bias, int S, int M, int N, long pBS)
{
    int b = blockIdx.z;
    long idx = ((long)blockIdx.x * 256 + threadIdx.x) * 4;
    if (idx >= (long)M * N) return;
    const float* Pb = P + (long)b * S * pBS + idx;
    float4 a = *(const float4*)Pb;
    for (int s = 1; s < S; s++) {
        float4 v = *(const float4*)(Pb + (long)s * pBS);
        a.x += v.x; a.y += v.y; a.z += v.z; a.w += v.w;
    }
    int m = (int)(idx / N), n = (int)(idx % N);
    if (BIAS) { float bv = bias[m]; a.x += bv; a.y += bv; a.z += bv; a.w += bv; }
    float av[4] = {a.x, a.y, a.z, a.w};
    if (!TRANS) {
        __bf16* o = out + (long)b * M * N + idx;
        o[0] = (__bf16)av[0]; o[1] = (__bf16)av[1]; o[2] = (__bf16)av[2]; o[3] = (__bf16)av[3];
    } else {
#pragma unroll
        for (int j = 0; j < 4; j++)
            out[(long)b * M * N + (long)(n + j) * M + m] = (__bf16)av[j];
    }
}

// ---------------- fused Linformer attention ----------------
__global__ __launch_bounds__(256, 2) void attn_fused(
    const __bf16* __restrict__ Q, const __bf16* __restrict__ KP,
    const __bf16* __restrict__ VPt, __bf16* __restrict__ O)
{
    __shared__ __bf16 plds[4][4096];
    const int tid = threadIdx.x, lane = tid & 63, wave = tid >> 6;
    const int l15 = lane & 15, l4 = lane >> 4;
    const int h = blockIdx.y, b = blockIdx.z;
    const long row0 = (long)b * 4096 + (long)blockIdx.x * 64 + wave * 16;

    bf16x8 aq[2];
#pragma unroll
    for (int ks = 0; ks < 2; ks++)
        aq[ks] = *(const bf16x8*)(Q + (row0 + l15) * 1024 + h * 64 + ks * 32 + l4 * 8);

    f32x4 s[16];
#pragma unroll
    for (int f = 0; f < 16; f++) {
        f32x4 a = (f32x4){0.f, 0.f, 0.f, 0.f};
#pragma unroll
        for (int ks = 0; ks < 2; ks++) {
            bf16x8 bk = *(const bf16x8*)(KP + ((long)b * 256 + f * 16 + l15) * 1024 + h * 64 + ks * 32 + l4 * 8);
            a = __builtin_amdgcn_mfma_f32_16x16x32_bf16(aq[ks], bk, a, 0, 0, 0);
        }
        s[f] = a;
    }

    const float scale = 0.125f;
#pragma unroll
    for (int i = 0; i < 4; i++) {
        float m_ = -3.4e38f;
#pragma unroll
        for (int f = 0; f < 16; f++) { float v = s[f][i] * scale; s[f][i] = v; m_ = fmaxf(m_, v); }
#pragma unroll
        for (int msk = 1; msk < 16; msk <<= 1) m_ = fmaxf(m_, __shfl_xor(m_, msk));
        float su = 0.f;
#pragma unroll
        for (int f = 0; f < 16; f++) { float e = expf(s[f][i] - m_); s[f][i] = e; su += e; }
#pragma unroll
        for (int msk = 1; msk < 16; msk <<= 1) su += __shfl_xor(su, msk);
        float inv = 1.f / su;
#pragma unroll
        for (int f = 0; f < 16; f++) s[f][i] *= inv;
    }

    __bf16* pl = plds[wave];
#pragma unroll
    for (int f = 0; f < 16; f++)
#pragma unroll
        for (int i = 0; i < 4; i++) {
            int r = l4 * 4 + i, c = f * 16 + l15;
            int off = r * 256 + ((((c >> 3) ^ (r & 7)) << 3) | (c & 7));
            pl[off] = (__bf16)s[f][i];
        }

    f32x4 o[4];
#pragma unroll
    for (int f2 = 0; f2 < 4; f2++) o[f2] = (f32x4){0.f, 0.f, 0.f, 0.f};
#pragma unroll
    for (int ks = 0; ks < 8; ks++) {
        int kk = ks * 32 + l4 * 8;
        int off = l15 * 256 + (((kk >> 3) ^ (l15 & 7)) << 3);
        bf16x8 ap = *(const bf16x8*)(pl + off);
#pragma unroll
        for (int f2 = 0; f2 < 4; f2++) {
            bf16x8 bv = *(const bf16x8*)(VPt + ((long)b * 1024 + h * 64 + f2 * 16 + l15) * 256 + kk);
            o[f2] = __builtin_amdgcn_mfma_f32_16x16x32_bf16(ap, bv, o[f2], 0, 0, 0);
        }
    }
#pragma unroll
    for (int f2 = 0; f2 < 4; f2++)
#pragma unroll
        for (int i = 0; i < 4; i++)
            O[(row0 + l4 * 4 + i) * 1024 + h * 64 + f2 * 16 + l15] = (__bf16)o[f2][i];
}

// ---------------- LayerNorm (row=1024), writes f32 + bf16 ----------------
__global__ __launch_bounds__(256) void ln_kernel(const float* __restrict__ y,
    const float* __restrict__ g, const float* __restrict__ b,
    float* __restrict__ xout, __bf16* __restrict__ xb)
{
    const int row = blockIdx.x;
    const int t = threadIdx.x;
    const float4 v = ((const float4*)(y + (long)row * 1024))[t];
    float s  = v.x + v.y + v.z + v.w;
    float ss = v.x * v.x + v.y * v.y + v.z * v.z + v.w * v.w;
#pragma unroll
    for (int m = 1; m < 64; m <<= 1) { s += __shfl_xor(s, m); ss += __shfl_xor(ss, m); }
    __shared__ float red[2][4];
    const int wave = t >> 6, lane = t & 63;
    if (lane == 0) { red[0][wave] = s; red[1][wave] = ss; }
    __syncthreads();
    s  = red[0][0] + red[0][1] + red[0][2] + red[0][3];
    ss = red[1][0] + red[1][1] + red[1][2] + red[1][3];
    const float mu = s * (1.f / 1024.f);
    const float var = ss * (1.f / 1024.f) - mu * mu;
    const float rs = rsqrtf(var + 1e-5f);
    const float4 gv = ((const float4*)g)[t];
    const float4 bv = ((const float4*)b)[t];
    float o0 = (v.x - mu) * rs * gv.x + bv.x;
    float o1 = (v.y - mu) * rs * gv.y + bv.y;
    float o2 = (v.z - mu) * rs * gv.z + bv.z;
    float o3 = (v.w - mu) * rs * gv.w + bv.w;
    float4 ov; ov.x = o0; ov.y = o1; ov.z = o2; ov.w = o3;
    ((float4*)(xout + (long)row * 1024))[t] = ov;
    __bf16* xr = xb + (long)row * 1024 + t * 4;
    xr[0] = (__bf16)o0; xr[1] = (__bf16)o1; xr[2] = (__bf16)o2; xr[3] = (__bf16)o3;
}

// ---------------- host launch ----------------
extern "C" void kernel_launch(void* const* d_in, const int* in_sizes, int n_in,
                              void* d_out, int out_size, void* d_ws, size_t ws_size,
                              hipStream_t stream) {
    const float* x   = (const float*)d_in[0];
    const float* Wq  = (const float*)d_in[1];
    const float* Wk  = (const float*)d_in[2];
    const float* Wv  = (const float*)d_in[3];
    const float* Wo  = (const float*)d_in[4];
    const float* bo  = (const float*)d_in[5];
    const float* Ew  = (const float*)d_in[6];
    const float* Eb  = (const float*)d_in[7];
    const float* W1  = (const float*)d_in[8];
    const float* b1  = (const float*)d_in[9];
    const float* W2  = (const float*)d_in[10];
    const float* b2  = (const float*)d_in[11];
    const float* lng = (const float*)d_in[12];
    const float* lnb = (const float*)d_in[13];
    float* xout = (float*)d_out;

    char* base = (char*)d_ws;
    size_t off = 0;
    auto alloc = [&](size_t bytes) { void* p = base + off; off += (bytes + 255) & ~(size_t)255; return p; };
    __bf16* Wqt = (__bf16*)alloc(2ll * 1024 * 1024 * 2);
    __bf16* Wkt = (__bf16*)alloc(2ll * 1024 * 1024 * 2);
    __bf16* Wvt = (__bf16*)alloc(2ll * 1024 * 1024 * 2);
    __bf16* Wot = (__bf16*)alloc(2ll * 1024 * 1024 * 2);
    __bf16* W1t = (__bf16*)alloc(2ll * 1024 * 4096 * 2);
    __bf16* W2t = (__bf16*)alloc(2ll * 1024 * 4096 * 2);
    __bf16* Ewb = (__bf16*)alloc(256ll * 4096 * 2);
    __bf16* xb  = (__bf16*)alloc(8192ll * 1024 * 2);
    __bf16* xbT = (__bf16*)alloc(2ll * 1024 * 4096 * 2);
    float*  y   = (float*) alloc(8192ll * 1024 * 4);
    __bf16* xp  = (__bf16*)alloc(2ll * 256 * 1024 * 2);
    __bf16* KPb = (__bf16*)alloc(2ll * 256 * 1024 * 2);
    __bf16* VPt = (__bf16*)alloc(2ll * 1024 * 256 * 2);
    __bf16* big = (__bf16*)alloc(8192ll * 4096 * 2);   // 64 MB scratch region
    // aliases within big (all uses strictly sequential):
    float*  xpP = (float*)big;                          // [16][256*1024] f32 = 16MB
    float*  kpP = (float*)((char*)big + (16ll << 20));  // [8][256*1024]  f32 =  8MB
    float*  vpP = (float*)((char*)big + (24ll << 20));  // [8][256*1024]  f32 =  8MB
    __bf16* Qb  = big;                                  // [8192][1024] (over xpP, dead)
    __bf16* Ob  = big + (16ll << 20);                   // [8192][1024] (over kpP/vpP, dead)
    __bf16* hbuf = big;                                 // [8192][4096] (FF stage)

    cvt_f32_bf16<<<2048, 256, 0, stream>>>(x, xb, 8388608);
    cvt_f32_bf16<<<1024, 256, 0, stream>>>(Ew, Ewb, 1048576);
    transpose_cvt<<<dim3(2, 32, 32),  dim3(32, 8), 0, stream>>>(Wq, Wqt, 64, 1024, 65536, 65536);
    transpose_cvt<<<dim3(2, 32, 32),  dim3(32, 8), 0, stream>>>(Wk, Wkt, 64, 1024, 65536, 65536);
    transpose_cvt<<<dim3(2, 32, 32),  dim3(32, 8), 0, stream>>>(Wv, Wvt, 64, 1024, 65536, 65536);
    transpose_cvt<<<dim3(32, 32, 2),  dim3(32, 8), 0, stream>>>(Wo, Wot, 1024, 1024, 1048576, 1048576);
    transpose_cvt<<<dim3(128, 32, 2), dim3(32, 8), 0, stream>>>(W1, W1t, 4096, 1024, 4194304, 4194304);
    transpose_cvt<<<dim3(32, 128, 2), dim3(32, 8), 0, stream>>>(W2, W2t, 1024, 4096, 4194304, 4194304);

    for (int l = 0; l < 2; l++) {
        const __bf16* Wqt_l = Wqt + (long)l * 1048576;
        const __bf16* Wkt_l = Wkt + (long)l * 1048576;
        const __bf16* Wvt_l = Wvt + (long)l * 1048576;
        const __bf16* Wot_l = Wot + (long)l * 1048576;
        const __bf16* W1t_l = W1t + (long)l * 4194304;
        const __bf16* W2t_l = W2t + (long)l * 4194304;
        const float* res = (l == 0) ? x : xout;

        // xbT[b] = xb[b]^T
        transpose_bf16<<<dim3(32, 128, 2), dim3(32, 8), 0, stream>>>(xb, xbT, 4096, 1024);
        // xp = Ew @ x  (split-K 8)
        gemm128_split<<<dim3(2, 8, 16), 256, 0, stream>>>(
            Ewb, 4096, 0, xbT, 4096, 4194304, xpP, 262144, 1024, 512, 8);
        reduce_partials<false, false><<<dim3(256, 1, 2), 256, 0, stream>>>(
            xpP, xp, nullptr, 8, 256, 1024, 262144);
        // KP = xp @ Wk^T + Eb  (split-K 4)
        gemm128_split<<<dim3(2, 8, 8), 256, 0, stream>>>(
            xp, 1024, 262144, Wkt_l, 1024, 0, kpP, 262144, 1024, 256, 4);
        reduce_partials<true, false><<<dim3(256, 1, 2), 256, 0, stream>>>(
            kpP, KPb, Eb, 4, 256, 1024, 262144);
        // VPt = (xp @ Wv^T + Eb)^T
        gemm128_split<<<dim3(2, 8, 8), 256, 0, stream>>>(
            xp, 1024, 262144, Wvt_l, 1024, 0, vpP, 262144, 1024, 256, 4);
        reduce_partials<true, true><<<dim3(256, 1, 2), 256, 0, stream>>>(
            vpP, VPt, Eb, 4, 256, 1024, 262144);
        // Q = xb @ Wq^T
        gemm256<128, 4, 2, false, false, false, false, 1><<<dim3(32, 8), 512, 0, stream>>>(
            xb, 1024, Wqt_l, 1024, (void*)Qb, 1024, nullptr, nullptr, nullptr, 0, 1024);
        // attention
        attn_fused<<<dim3(64, 16, 2), 256, 0, stream>>>(Qb, KPb, VPt, Ob);
        // attn_out = O @ Wo^T + bo + residual
        gemm256<128, 4, 2, false, true, false, true, 0><<<dim3(32, 8), 512, 0, stream>>>(
            Ob, 1024, Wot_l, 1024, (void*)y, 1024, nullptr, bo + l * 1024, res, 1024, 1024);
        ln_kernel<<<8192, 256, 0, stream>>>(y, lng + (2 * l + 0) * 1024, lnb + (2 * l + 0) * 1024, xout, xb);
        // h = gelu(x @ W1 + b1)
        gemm256<256, 2, 4, false, true, true, false, 1><<<dim3(32, 16), 512, 0, stream>>>(
            xb, 1024, W1t_l, 1024, (void*)hbuf, 4096, nullptr, b1 + l * 4096, nullptr, 0, 1024);
        // ff = h @ W2 + b2 + residual
        gemm256<128, 4, 2, false, true, false, true, 0><<<dim3(32, 8), 512, 0, stream>>>(
            hbuf, 4096, W2t_l, 4096, (void*)y, 1024, nullptr, b2 + l * 1024, xout, 1024, 4096);
        ln_kernel<<<8192, 256, 0, stream>>>(y, lng + (2 * l + 1) * 1024, lnb + (2 * l + 1) * 1024, xout, xb);
    }
}

// Round 4
// 923.206 us; speedup vs baseline: 3.4034x; 1.0449x over previous
//
#include <hip/hip_runtime.h>
#include <hip/hip_bf16.h>
#include <math.h>

// ---------------- types ----------------
typedef __bf16 bf16x8 __attribute__((ext_vector_type(8)));
typedef float f32x4 __attribute__((ext_vector_type(4)));

// ---------------- conversion kernels ----------------
__global__ void cvt_f32_bf16(const float* __restrict__ in, __bf16* __restrict__ out, long n) {
    long i = ((long)blockIdx.x * 256 + threadIdx.x) * 4;
    long stride = (long)gridDim.x * 1024;
    for (; i < n; i += stride) {
        float4 v = *(const float4*)(in + i);
        out[i + 0] = (__bf16)v.x;
        out[i + 1] = (__bf16)v.y;
        out[i + 2] = (__bf16)v.z;
        out[i + 3] = (__bf16)v.w;
    }
}

// transpose + convert: in f32 [M][N] (ldin) -> out bf16 [N][M] (ldout), batched over z
__global__ void transpose_cvt(const float* __restrict__ in, __bf16* __restrict__ out,
                              int ldin, int ldout, long inBS, long outBS) {
    __shared__ __bf16 tile[32][33];
    in  += (long)blockIdx.z * inBS;
    out += (long)blockIdx.z * outBS;
    int n0 = blockIdx.x * 32, m0 = blockIdx.y * 32;
    for (int i = threadIdx.y; i < 32; i += 8)
        tile[i][threadIdx.x] = (__bf16)in[(long)(m0 + i) * ldin + n0 + threadIdx.x];
    __syncthreads();
    for (int i = threadIdx.y; i < 32; i += 8)
        out[(long)(n0 + i) * ldout + m0 + threadIdx.x] = tile[threadIdx.x][i];
}

// bf16 transpose: in [rows][cols] -> out [cols][rows], batched over z
__global__ void transpose_bf16(const __bf16* __restrict__ in, __bf16* __restrict__ out,
                               int rows, int cols) {
    __shared__ __bf16 tile[32][33];
    in  += (long)blockIdx.z * rows * cols;
    out += (long)blockIdx.z * rows * cols;
    int c0 = blockIdx.x * 32, r0 = blockIdx.y * 32;
    for (int i = threadIdx.y; i < 32; i += 8)
        tile[i][threadIdx.x] = in[(long)(r0 + i) * cols + c0 + threadIdx.x];
    __syncthreads();
    for (int i = threadIdx.y; i < 32; i += 8)
        out[(long)(c0 + i) * rows + r0 + threadIdx.x] = tile[threadIdx.x][i];
}

// ---- frag_cvt: W f32 [K][N] -> bf16 MFMA-fragment chunks -------------------
// chunk c = nblk*(K/32) + kblk (nblk = n/16, kblk = k/32); within chunk:
// elem lane*8+e = W[kblk*32 + (lane>>4)*8 + e][nblk*16 + (lane&15)]
// grid (N/64, K/32, Z), block 256.
__global__ void frag_cvt(const float* __restrict__ in, __bf16* __restrict__ out,
                         int K, int N, long inBS, long outBS) {
    __shared__ float tile[32][65];
    in  += (long)blockIdx.z * inBS;
    out += (long)blockIdx.z * outBS;
    const int n0 = blockIdx.x * 64, k0 = blockIdx.y * 32;
    for (int r = threadIdx.x >> 6; r < 32; r += 4)
        tile[r][threadIdx.x & 63] = in[(long)(k0 + r) * N + n0 + (threadIdx.x & 63)];
    __syncthreads();
    const int cl = threadIdx.x >> 6, lane = threadIdx.x & 63;
    const int nl = cl * 16 + (lane & 15);
    const int kl = (lane >> 4) * 8;
    const long chunk = (long)((n0 >> 4) + cl) * (K >> 5) + (k0 >> 5);
    bf16x8 v;
#pragma unroll
    for (int e = 0; e < 8; e++) v[e] = (__bf16)tile[kl + e][nl];
    *(bf16x8*)(out + chunk * 512 + lane * 8) = v;
}

// ============ gemm_bdir: BM=256 x BN tile, A in LDS ring-3, B direct ============
// C[M,N] = A[M,K] @ B^T with B given in fragment layout (frag_cvt). 512 thr, 8 waves
// (2M x 4N). Counted vmcnt(4) per K-tile (never 0 mid-loop), one barrier per K-tile.
// OUT: 0 = f32, 1 = bf16
template<int BN, bool ROWB, bool COLB, bool GELUF, bool RES, int OUT>
__global__ __launch_bounds__(512, 1) void gemm_bdir(
    const __bf16* __restrict__ A, int lda,
    const __bf16* __restrict__ Bf,
    void* __restrict__ outp, int ldc,
    const float* __restrict__ rowBias,
    const float* __restrict__ colBias,
    const float* __restrict__ res, int ldres,
    int K)
{
    constexpr int N_REP = BN >> 6;          // frags per wave along N (4 or 2)
    constexpr int M_REP = 8;                // 128 rows per wave
    __shared__ __bf16 Asm[3 * 256 * 64];    // 96KB: ring-3 of 256x64 A tiles

    const int tid = threadIdx.x, lane = tid & 63, wave = tid >> 6;
    const int l15 = lane & 15, l4 = lane >> 4;
    const int wm = wave >> 2, wn = wave & 3;

    // XCD swizzle: XCD owns a contiguous N-panel chunk x all M (B-panel L2-resident)
    int bx, by;
    {
        int id = blockIdx.y * gridDim.x + blockIdx.x;
        int xcd = id & 7, local = id >> 3;
        int nx = gridDim.y >> 3;            // grid.y % 8 == 0 for all our launches
        by = xcd * nx + local / gridDim.x;
        bx = local % gridDim.x;
    }
    const long m0 = (long)bx * 256, n0 = (long)by * BN;

    // A staging: wave stages rows wave*32..+32 (4 ops x 8 rows); source pre-swizzled
    // so LDS[r][u] = G[r][u ^ (r&7)] (16B units), proven 0-conflict (round 2).
    const int srow = lane >> 3;                  // 0..7
    const int gunit = ((lane & 7) ^ srow) << 3;  // element offset
    const __bf16* Abp = A + (m0 + wave * 32 + srow) * (long)lda + gunit;

    auto stage = [&](int buf, int t) {
        __bf16* dst = Asm + buf * 16384 + wave * 2048;
        const __bf16* src = Abp + (long)t * 64;
#pragma unroll
        for (int j = 0; j < 4; j++)
            __builtin_amdgcn_global_load_lds(
                (const __attribute__((address_space(1))) unsigned int*)(src + (long)j * 8 * lda),
                (__attribute__((address_space(3))) unsigned int*)(dst + j * 512), 16, 0, 0);
    };

    const int kb5 = K >> 5;
    const int nblk0 = (int)(n0 >> 4) + wn * N_REP;

    f32x4 acc[M_REP][N_REP];
#pragma unroll
    for (int mi = 0; mi < M_REP; mi++)
#pragma unroll
        for (int ni = 0; ni < N_REP; ni++) acc[mi][ni] = (f32x4){0.f, 0.f, 0.f, 0.f};

    const int NT = K >> 6;
    stage(0, 0);
    stage(1, 1);
    int buf = 0, sbuf = 2;

    for (int t = 0; t < NT; t++) {
        if (t + 1 < NT) { asm volatile("s_waitcnt vmcnt(4)" ::: "memory"); }
        else            { asm volatile("s_waitcnt vmcnt(0)" ::: "memory"); }
        __builtin_amdgcn_s_barrier();

        // B fragments for this K-tile: coalesced dwordx4 from L2 (issued first)
        bf16x8 bfv[2][N_REP];
#pragma unroll
        for (int ks = 0; ks < 2; ks++)
#pragma unroll
            for (int ni = 0; ni < N_REP; ni++)
                bfv[ks][ni] = *(const bf16x8*)(Bf + ((long)(nblk0 + ni) * kb5 + t * 2 + ks) * 512 + lane * 8);
        __builtin_amdgcn_sched_barrier(0);

        if (t + 2 < NT) stage(sbuf, t + 2);

        const __bf16* Abuf = Asm + buf * 16384;
#pragma unroll
        for (int ks = 0; ks < 2; ks++) {
            bf16x8 af[M_REP];
#pragma unroll
            for (int mi = 0; mi < M_REP; mi++)
                af[mi] = *(const bf16x8*)(Abuf + (wm * 128 + mi * 16 + l15) * 64 + (((ks * 4 + l4) ^ (l15 & 7)) << 3));
            __builtin_amdgcn_s_setprio(1);
#pragma unroll
            for (int mi = 0; mi < M_REP; mi++)
#pragma unroll
                for (int ni = 0; ni < N_REP; ni++)
                    acc[mi][ni] = __builtin_amdgcn_mfma_f32_16x16x32_bf16(af[mi], bfv[ks][ni], acc[mi][ni], 0, 0, 0);
            __builtin_amdgcn_s_setprio(0);
        }
        buf = (buf == 2) ? 0 : buf + 1;
        sbuf = (sbuf == 2) ? 0 : sbuf + 1;
    }

    float* outf = (float*)outp;
    __bf16* outb = (__bf16*)outp;
#pragma unroll
    for (int mi = 0; mi < M_REP; mi++)
#pragma unroll
        for (int ni = 0; ni < N_REP; ni++) {
            long gmb = m0 + wm * 128 + mi * 16 + l4 * 4;
            long gc  = n0 + wn * (BN / 4) + ni * 16 + l15;
#pragma unroll
            for (int i = 0; i < 4; i++) {
                long gm = gmb + i;
                float v = acc[mi][ni][i];
                if (ROWB)  v += rowBias[gm];
                if (COLB)  v += colBias[gc];
                if (GELUF) v = 0.5f * v * (1.f + erff(v * 0.70710678118f));
                if (RES)   v += res[gm * (long)ldres + gc];
                if (OUT == 0) outf[gm * (long)ldc + gc] = v;
                else          outb[gm * (long)ldc + gc] = (__bf16)v;
            }
        }
}

// ========== gemm128_split: 128x128 tile split-K, writes f32 partials ==========
__global__ __launch_bounds__(256, 2) void gemm128_split(
    const __bf16* __restrict__ A, int lda, long aBS,
    const __bf16* __restrict__ Bt, int ldb, long bBS,
    float* __restrict__ P, long cBS, int ldc,
    int Ksplit, int S)
{
    __shared__ __bf16 Asm[128 * 64];
    __shared__ __bf16 Bsm[128 * 64];
    const int tid = threadIdx.x;
    const int lane = tid & 63, wave = tid >> 6;
    const int wm = wave >> 1, wn = wave & 1;
    const int l15 = lane & 15, l4 = lane >> 4;
    const long m0 = (long)blockIdx.x * 128, n0 = (long)blockIdx.y * 128;
    const long zb = blockIdx.z / S;
    const int  sp = blockIdx.z % S;
    A  += zb * aBS + (long)sp * Ksplit;
    Bt += zb * bBS + (long)sp * Ksplit;

    const int srow8 = lane >> 3;
    const int gunit = ((lane & 7) ^ srow8) << 3;
    const __bf16* Abase = A + (m0 + wave * 8 + srow8) * (long)lda + gunit;
    const __bf16* Bbase = Bt + (n0 + wave * 8 + srow8) * (long)ldb + gunit;
    __bf16* AsmW = Asm + wave * 8 * 64;
    __bf16* BsmW = Bsm + wave * 8 * 64;
    const int swz_r = l15 & 7;

    f32x4 acc[4][4];
#pragma unroll
    for (int mi = 0; mi < 4; mi++)
#pragma unroll
        for (int ni = 0; ni < 4; ni++) acc[mi][ni] = (f32x4){0.f, 0.f, 0.f, 0.f};

    for (int k0 = 0; k0 < Ksplit; k0 += 64) {
        __syncthreads();
#pragma unroll
        for (int p = 0; p < 4; p++) {
            __builtin_amdgcn_global_load_lds(
                (const __attribute__((address_space(1))) unsigned int*)(Abase + (long)p * 32 * lda + k0),
                (__attribute__((address_space(3))) unsigned int*)(AsmW + p * 32 * 64), 16, 0, 0);
            __builtin_amdgcn_global_load_lds(
                (const __attribute__((address_space(1))) unsigned int*)(Bbase + (long)p * 32 * ldb + k0),
                (__attribute__((address_space(3))) unsigned int*)(BsmW + p * 32 * 64), 16, 0, 0);
        }
        asm volatile("s_waitcnt vmcnt(0)" ::: "memory");
        __syncthreads();
#pragma unroll
        for (int ks = 0; ks < 2; ks++) {
            bf16x8 af[4], bfv[4];
#pragma unroll
            for (int mi = 0; mi < 4; mi++)
                af[mi] = *(const bf16x8*)(Asm + (wm * 64 + mi * 16 + l15) * 64 + (((ks * 4 + l4) ^ swz_r) << 3));
#pragma unroll
            for (int ni = 0; ni < 4; ni++)
                bfv[ni] = *(const bf16x8*)(Bsm + (wn * 64 + ni * 16 + l15) * 64 + (((ks * 4 + l4) ^ swz_r) << 3));
#pragma unroll
            for (int mi = 0; mi < 4; mi++)
#pragma unroll
                for (int ni = 0; ni < 4; ni++)
                    acc[mi][ni] = __builtin_amdgcn_mfma_f32_16x16x32_bf16(af[mi], bfv[ni], acc[mi][ni], 0, 0, 0);
        }
    }

    float* out = P + (long)blockIdx.z * cBS;
#pragma unroll
    for (int mi = 0; mi < 4; mi++)
#pragma unroll
        for (int ni = 0; ni < 4; ni++) {
            long gmb = m0 + wm * 64 + mi * 16 + l4 * 4;
            long gc  = n0 + wn * 64 + ni * 16 + l15;
#pragma unroll
            for (int i = 0; i < 4; i++)
                out[(gmb + i) * (long)ldc + gc] = acc[mi][ni][i];
        }
}

// ---------- reduce S f32 partials -> bf16 (+row bias, optional transposed write) ----------
template<bool BIAS, bool TRANS>
__global__ __launch_bounds__(256) void reduce_partials(
    const float* __restrict__ P, __bf16* __restrict__ out,
    const float* __restrict__ bias, int S, int M, int N, long pBS)
{
    int b = blockIdx.z;
    long idx = ((long)blockIdx.x * 256 + threadIdx.x) * 4;
    if (idx >= (long)M * N) return;
    const float* Pb = P + (long)b * S * pBS + idx;
    float4 a = *(const float4*)Pb;
    for (int s = 1; s < S; s++) {
        float4 v = *(const float4*)(Pb + (long)s * pBS);
        a.x += v.x; a.y += v.y; a.z += v.z; a.w += v.w;
    }
    int m = (int)(idx / N), n = (int)(idx % N);
    if (BIAS) { float bv = bias[m]; a.x += bv; a.y += bv; a.z += bv; a.w += bv; }
    float av[4] = {a.x, a.y, a.z, a.w};
    if (!TRANS) {
        __bf16* o = out + (long)b * M * N + idx;
        o[0] = (__bf16)av[0]; o[1] = (__bf16)av[1]; o[2] = (__bf16)av[2]; o[3] = (__bf16)av[3];
    } else {
#pragma unroll
        for (int j = 0; j < 4; j++)
            out[(long)b * M * N + (long)(n + j) * M + m] = (__bf16)av[j];
    }
}

// ---------------- fused Linformer attention ----------------
__global__ __launch_bounds__(256, 2) void attn_fused(
    const __bf16* __restrict__ Q, const __bf16* __restrict__ KP,
    const __bf16* __restrict__ VPt, __bf16* __restrict__ O)
{
    __shared__ __bf16 plds[4][4096];
    const int tid = threadIdx.x, lane = tid & 63, wave = tid >> 6;
    const int l15 = lane & 15, l4 = lane >> 4;
    const int h = blockIdx.y, b = blockIdx.z;
    const long row0 = (long)b * 4096 + (long)blockIdx.x * 64 + wave * 16;

    bf16x8 aq[2];
#pragma unroll
    for (int ks = 0; ks < 2; ks++)
        aq[ks] = *(const bf16x8*)(Q + (row0 + l15) * 1024 + h * 64 + ks * 32 + l4 * 8);

    f32x4 s[16];
#pragma unroll
    for (int f = 0; f < 16; f++) {
        f32x4 a = (f32x4){0.f, 0.f, 0.f, 0.f};
#pragma unroll
        for (int ks = 0; ks < 2; ks++) {
            bf16x8 bk = *(const bf16x8*)(KP + ((long)b * 256 + f * 16 + l15) * 1024 + h * 64 + ks * 32 + l4 * 8);
            a = __builtin_amdgcn_mfma_f32_16x16x32_bf16(aq[ks], bk, a, 0, 0, 0);
        }
        s[f] = a;
    }

    const float scale = 0.125f;
#pragma unroll
    for (int i = 0; i < 4; i++) {
        float m_ = -3.4e38f;
#pragma unroll
        for (int f = 0; f < 16; f++) { float v = s[f][i] * scale; s[f][i] = v; m_ = fmaxf(m_, v); }
#pragma unroll
        for (int msk = 1; msk < 16; msk <<= 1) m_ = fmaxf(m_, __shfl_xor(m_, msk));
        float su = 0.f;
#pragma unroll
        for (int f = 0; f < 16; f++) { float e = expf(s[f][i] - m_); s[f][i] = e; su += e; }
#pragma unroll
        for (int msk = 1; msk < 16; msk <<= 1) su += __shfl_xor(su, msk);
        float inv = 1.f / su;
#pragma unroll
        for (int f = 0; f < 16; f++) s[f][i] *= inv;
    }

    __bf16* pl = plds[wave];
#pragma unroll
    for (int f = 0; f < 16; f++)
#pragma unroll
        for (int i = 0; i < 4; i++) {
            int r = l4 * 4 + i, c = f * 16 + l15;
            int off = r * 256 + ((((c >> 3) ^ (r & 7)) << 3) | (c & 7));
            pl[off] = (__bf16)s[f][i];
        }

    f32x4 o[4];
#pragma unroll
    for (int f2 = 0; f2 < 4; f2++) o[f2] = (f32x4){0.f, 0.f, 0.f, 0.f};
#pragma unroll
    for (int ks = 0; ks < 8; ks++) {
        int kk = ks * 32 + l4 * 8;
        int off = l15 * 256 + (((kk >> 3) ^ (l15 & 7)) << 3);
        bf16x8 ap = *(const bf16x8*)(pl + off);
#pragma unroll
        for (int f2 = 0; f2 < 4; f2++) {
            bf16x8 bv = *(const bf16x8*)(VPt + ((long)b * 1024 + h * 64 + f2 * 16 + l15) * 256 + kk);
            o[f2] = __builtin_amdgcn_mfma_f32_16x16x32_bf16(ap, bv, o[f2], 0, 0, 0);
        }
    }
#pragma unroll
    for (int f2 = 0; f2 < 4; f2++)
#pragma unroll
        for (int i = 0; i < 4; i++)
            O[(row0 + l4 * 4 + i) * 1024 + h * 64 + f2 * 16 + l15] = (__bf16)o[f2][i];
}

// ---------------- LayerNorm (row=1024), writes f32 + bf16 ----------------
__global__ __launch_bounds__(256) void ln_kernel(const float* __restrict__ y,
    const float* __restrict__ g, const float* __restrict__ b,
    float* __restrict__ xout, __bf16* __restrict__ xb)
{
    const int row = blockIdx.x;
    const int t = threadIdx.x;
    const float4 v = ((const float4*)(y + (long)row * 1024))[t];
    float s  = v.x + v.y + v.z + v.w;
    float ss = v.x * v.x + v.y * v.y + v.z * v.z + v.w * v.w;
#pragma unroll
    for (int m = 1; m < 64; m <<= 1) { s += __shfl_xor(s, m); ss += __shfl_xor(ss, m); }
    __shared__ float red[2][4];
    const int wave = t >> 6, lane = t & 63;
    if (lane == 0) { red[0][wave] = s; red[1][wave] = ss; }
    __syncthreads();
    s  = red[0][0] + red[0][1] + red[0][2] + red[0][3];
    ss = red[1][0] + red[1][1] + red[1][2] + red[1][3];
    const float mu = s * (1.f / 1024.f);
    const float var = ss * (1.f / 1024.f) - mu * mu;
    const float rs = rsqrtf(var + 1e-5f);
    const float4 gv = ((const float4*)g)[t];
    const float4 bv = ((const float4*)b)[t];
    float o0 = (v.x - mu) * rs * gv.x + bv.x;
    float o1 = (v.y - mu) * rs * gv.y + bv.y;
    float o2 = (v.z - mu) * rs * gv.z + bv.z;
    float o3 = (v.w - mu) * rs * gv.w + bv.w;
    float4 ov; ov.x = o0; ov.y = o1; ov.z = o2; ov.w = o3;
    ((float4*)(xout + (long)row * 1024))[t] = ov;
    __bf16* xr = xb + (long)row * 1024 + t * 4;
    xr[0] = (__bf16)o0; xr[1] = (__bf16)o1; xr[2] = (__bf16)o2; xr[3] = (__bf16)o3;
}

// ---------------- host launch ----------------
extern "C" void kernel_launch(void* const* d_in, const int* in_sizes, int n_in,
                              void* d_out, int out_size, void* d_ws, size_t ws_size,
                              hipStream_t stream) {
    const float* x   = (const float*)d_in[0];
    const float* Wq  = (const float*)d_in[1];
    const float* Wk  = (const float*)d_in[2];
    const float* Wv  = (const float*)d_in[3];
    const float* Wo  = (const float*)d_in[4];
    const float* bo  = (const float*)d_in[5];
    const float* Ew  = (const float*)d_in[6];
    const float* Eb  = (const float*)d_in[7];
    const float* W1  = (const float*)d_in[8];
    const float* b1  = (const float*)d_in[9];
    const float* W2  = (const float*)d_in[10];
    const float* b2  = (const float*)d_in[11];
    const float* lng = (const float*)d_in[12];
    const float* lnb = (const float*)d_in[13];
    float* xout = (float*)d_out;

    char* base = (char*)d_ws;
    size_t off = 0;
    auto alloc = [&](size_t bytes) { void* p = base + off; off += (bytes + 255) & ~(size_t)255; return p; };
    __bf16* Wkt = (__bf16*)alloc(2ll * 1024 * 1024 * 2);
    __bf16* Wvt = (__bf16*)alloc(2ll * 1024 * 1024 * 2);
    __bf16* Wqf = (__bf16*)alloc(2ll * 1024 * 1024 * 2);   // fragment layouts
    __bf16* Wof = (__bf16*)alloc(2ll * 1024 * 1024 * 2);
    __bf16* W1f = (__bf16*)alloc(2ll * 1024 * 4096 * 2);
    __bf16* W2f = (__bf16*)alloc(2ll * 1024 * 4096 * 2);
    __bf16* Ewb = (__bf16*)alloc(256ll * 4096 * 2);
    __bf16* xb  = (__bf16*)alloc(8192ll * 1024 * 2);
    __bf16* xbT = (__bf16*)alloc(2ll * 1024 * 4096 * 2);
    float*  y   = (float*) alloc(8192ll * 1024 * 4);
    __bf16* xp  = (__bf16*)alloc(2ll * 256 * 1024 * 2);
    __bf16* KPb = (__bf16*)alloc(2ll * 256 * 1024 * 2);
    __bf16* VPt = (__bf16*)alloc(2ll * 1024 * 256 * 2);
    __bf16* big = (__bf16*)alloc(8192ll * 4096 * 2);   // 64 MB scratch region
    float*  xpP = (float*)big;                          // [16][256*1024] f32 = 16MB
    float*  kpP = (float*)((char*)big + (16ll << 20));  // [8][256*1024]  f32 =  8MB
    float*  vpP = (float*)((char*)big + (24ll << 20));  // [8][256*1024]  f32 =  8MB
    __bf16* Qb  = big;                                  // [8192][1024] (over xpP, dead)
    __bf16* Ob  = big + (16ll << 20);                   // [8192][1024] (over kpP/vpP, dead)
    __bf16* hbuf = big;                                 // [8192][4096] (FF stage)

    cvt_f32_bf16<<<2048, 256, 0, stream>>>(x, xb, 8388608);
    cvt_f32_bf16<<<1024, 256, 0, stream>>>(Ew, Ewb, 1048576);
    transpose_cvt<<<dim3(2, 32, 32),  dim3(32, 8), 0, stream>>>(Wk, Wkt, 64, 1024, 65536, 65536);
    transpose_cvt<<<dim3(2, 32, 32),  dim3(32, 8), 0, stream>>>(Wv, Wvt, 64, 1024, 65536, 65536);
    // fragment-layout weights (B-direct path)
    frag_cvt<<<dim3(1, 32, 32),  256, 0, stream>>>(Wq, Wqf, 1024, 64, 65536, 65536);
    frag_cvt<<<dim3(16, 32, 2),  256, 0, stream>>>(Wo, Wof, 1024, 1024, 1048576, 1048576);
    frag_cvt<<<dim3(64, 32, 2),  256, 0, stream>>>(W1, W1f, 1024, 4096, 4194304, 4194304);
    frag_cvt<<<dim3(16, 128, 2), 256, 0, stream>>>(W2, W2f, 4096, 1024, 4194304, 4194304);

    for (int l = 0; l < 2; l++) {
        const __bf16* Wkt_l = Wkt + (long)l * 1048576;
        const __bf16* Wvt_l = Wvt + (long)l * 1048576;
        const __bf16* Wqf_l = Wqf + (long)l * 1048576;
        const __bf16* Wof_l = Wof + (long)l * 1048576;
        const __bf16* W1f_l = W1f + (long)l * 4194304;
        const __bf16* W2f_l = W2f + (long)l * 4194304;
        const float* res = (l == 0) ? x : xout;

        // xbT[b] = xb[b]^T
        transpose_bf16<<<dim3(32, 128, 2), dim3(32, 8), 0, stream>>>(xb, xbT, 4096, 1024);
        // xp = Ew @ x  (split-K 8)
        gemm128_split<<<dim3(2, 8, 16), 256, 0, stream>>>(
            Ewb, 4096, 0, xbT, 4096, 4194304, xpP, 262144, 1024, 512, 8);
        reduce_partials<false, false><<<dim3(256, 1, 2), 256, 0, stream>>>(
            xpP, xp, nullptr, 8, 256, 1024, 262144);
        // KP = xp @ Wk^T + Eb  (split-K 4)
        gemm128_split<<<dim3(2, 8, 8), 256, 0, stream>>>(
            xp, 1024, 262144, Wkt_l, 1024, 0, kpP, 262144, 1024, 256, 4);
        reduce_partials<true, false><<<dim3(256, 1, 2), 256, 0, stream>>>(
            kpP, KPb, Eb, 4, 256, 1024, 262144);
        // VPt = (xp @ Wv^T + Eb)^T
        gemm128_split<<<dim3(2, 8, 8), 256, 0, stream>>>(
            xp, 1024, 262144, Wvt_l, 1024, 0, vpP, 262144, 1024, 256, 4);
        reduce_partials<true, true><<<dim3(256, 1, 2), 256, 0, stream>>>(
            vpP, VPt, Eb, 4, 256, 1024, 262144);
        // Q = xb @ Wq^T
        gemm_bdir<128, false, false, false, false, 1><<<dim3(32, 8), 512, 0, stream>>>(
            xb, 1024, Wqf_l, (void*)Qb, 1024, nullptr, nullptr, nullptr, 0, 1024);
        // attention
        attn_fused<<<dim3(64, 16, 2), 256, 0, stream>>>(Qb, KPb, VPt, Ob);
        // attn_out = O @ Wo^T + bo + residual
        gemm_bdir<128, false, true, false, true, 0><<<dim3(32, 8), 512, 0, stream>>>(
            Ob, 1024, Wof_l, (void*)y, 1024, nullptr, bo + l * 1024, res, 1024, 1024);
        ln_kernel<<<8192, 256, 0, stream>>>(y, lng + (2 * l + 0) * 1024, lnb + (2 * l + 0) * 1024, xout, xb);
        // h = gelu(x @ W1 + b1)
        gemm_bdir<256, false, true, true, false, 1><<<dim3(32, 16), 512, 0, stream>>>(
            xb, 1024, W1f_l, (void*)hbuf, 4096, nullptr, b1 + l * 4096, nullptr, 0, 1024);
        // ff = h @ W2 + b2 + residual
        gemm_bdir<128, false, true, false, true, 0><<<dim3(32, 8), 512, 0, stream>>>(
            hbuf, 4096, W2f_l, (void*)y, 1024, nullptr, b2 + l * 1024, xout, 1024, 4096);
        ln_kernel<<<8192, 256, 0, stream>>>(y, lng + (2 * l + 1) * 1024, lnb + (2 * l + 1) * 1024, xout, xb);
    }
}